// Round 8
// baseline (238.176 us; speedup 1.0000x reference)
//
#include <hip/hip_runtime.h>
#include <hip/hip_bf16.h>
#include <stdint.h>

#define BB 32768
#define NN 512
#define CHEB_IT 10
#define NSB 16    // solver blocks
#define NTILE 10  // upper-triangle 128x128 tiles of 512x512
#define NPART 32  // K-parts of 1024 b's each
#define BKC 32    // k2 K-chunk
#define NCH 32    // chunks per k2 block (1024/32)

typedef __attribute__((ext_vector_type(8))) short bf16x8;
typedef __attribute__((ext_vector_type(4))) float f32x4;

__device__ __forceinline__ void gld_lds16(const void* g, void* l) {
  typedef __attribute__((address_space(1))) const unsigned int gas_u32;
  typedef __attribute__((address_space(3))) unsigned int las_u32;
  __builtin_amdgcn_global_load_lds((gas_u32*)(uintptr_t)g,
                                   (las_u32*)(uint32_t)(uintptr_t)l, 16, 0, 0);
}

__device__ __forceinline__ unsigned short f2bf(float x) {
  __hip_bfloat16 h = __float2bfloat16(x);
  return *reinterpret_cast<unsigned short*>(&h);
}

__device__ __forceinline__ float bf2f(unsigned short u) {
  return __uint_as_float(((unsigned)u) << 16);
}

__device__ __forceinline__ float wave_reduce(float v) {
#pragma unroll
  for (int off = 32; off > 0; off >>= 1) v += __shfl_xor(v, off, 64);
  return v;
}

// 16-block cooperative Chebyshev solving Gamma v = SR, SPLIT across two host
// kernels: iters [k0i,k1i) run here; state (x,r,p full vectors) checkpointed in
// st[3*512]. LDS-resident 32-col Gamma slice per block; per-iter exchange =
// 512-float p via pglob + counter (r6/r7-verified protocol). theta/delta
// verified passing rounds 3-7.
__device__ void cheb_run(const unsigned short* __restrict__ Gbf,
                         const float* __restrict__ SR, float* __restrict__ st,
                         float* __restrict__ v_out, float* __restrict__ pglob,
                         unsigned int* __restrict__ ctr, char* smraw,
                         int k0i, int k1i) {
  unsigned short* Gs = (unsigned short*)smraw;  // [512][32]
  float* sp = (float*)(smraw + 32768);          // [512] current p
  float* red = sp + 512;                        // [8][32]
  const int t = threadIdx.x;  // 512 threads
  const int m = blockIdx.x;   // 0..15
#pragma unroll
  for (int h = 0; h < 4; ++h) {
    const int row = h * 128 + (t >> 2), sc = t & 3;
    gld_lds16(Gbf + (size_t)row * NN + m * 32 + sc * 8, Gs + row * 32 + sc * 8);
  }
  const float theta = 3.16f, delta = 2.19f;
  const float sigma1 = theta / delta;
  float rho = delta / theta;
  for (int q = 0; q < k0i; ++q) rho = 1.f / (2.f * sigma1 - rho);  // fast-forward
  float x = 0.f, r = 0.f, p = 0.f;
  if (k0i == 0) {
    if (t < 32) {
      float s = SR[m * 32 + t];
      r = s;
      p = s * (1.0f / theta);
    }
    sp[t] = SR[t] * (1.0f / theta);
  } else {
    if (t < 32) {
      x = st[m * 32 + t];
      r = st[512 + m * 32 + t];
      p = st[1024 + m * 32 + t];
    }
    sp[t] = st[1024 + t];
  }
  __syncthreads();  // drains vmcnt -> Gs staged; sp visible
  for (int k = k0i; k < k1i; ++k) {
    const int c2 = (t & 15) * 2, jseg = t >> 4;
    float a0 = 0.f, a1 = 0.f;
#pragma unroll
    for (int i = 0; i < 16; ++i) {
      const int j = jseg * 16 + i;
      const unsigned g2 = *(const unsigned*)(Gs + j * 32 + c2);
      const float pv = sp[j];
      a0 += bf2f((unsigned short)(g2 & 0xffffu)) * pv;
      a1 += bf2f((unsigned short)(g2 >> 16)) * pv;
    }
    a0 += __shfl_xor(a0, 16, 64); a0 += __shfl_xor(a0, 32, 64);
    a1 += __shfl_xor(a1, 16, 64); a1 += __shfl_xor(a1, 32, 64);
    const int lane = t & 63, wv = t >> 6;
    if (lane < 16) {
      red[wv * 32 + lane * 2] = a0;
      red[wv * 32 + lane * 2 + 1] = a1;
    }
    __syncthreads();
    const float rho_new = 1.f / (2.f * sigma1 - rho);
    if (t < 32) {
      float ap = 0.f;
#pragma unroll
      for (int w = 0; w < 8; ++w) ap += red[w * 32 + t];
      x += p;
      r -= ap;
      p = rho_new * rho * p + (2.f * rho_new / delta) * r;
      if (k + 1 < k1i)
        __hip_atomic_store(pglob + (k & 1) * 512 + m * 32 + t, p,
                           __ATOMIC_RELAXED, __HIP_MEMORY_SCOPE_AGENT);
    }
    rho = rho_new;
    if (k + 1 >= k1i) break;
    __threadfence();
    __syncthreads();
    if (t == 0) {
      __hip_atomic_fetch_add(ctr, 1u, __ATOMIC_RELEASE, __HIP_MEMORY_SCOPE_AGENT);
      const unsigned tgt = (unsigned)NSB * (unsigned)(k - k0i + 1);
      int guard = 0;
      while (__hip_atomic_load(ctr, __ATOMIC_ACQUIRE, __HIP_MEMORY_SCOPE_AGENT) < tgt) {
        if (++guard > (1 << 27)) break;  // fail loud rather than hang
        __builtin_amdgcn_s_sleep(8);
      }
    }
    __syncthreads();
    sp[t] = __hip_atomic_load(pglob + (k & 1) * 512 + t, __ATOMIC_RELAXED,
                              __HIP_MEMORY_SCOPE_AGENT);
    __syncthreads();
  }
  if (k1i >= CHEB_IT) {
    if (t < 32) v_out[m * 32 + t] = x;
  } else if (t < 32) {  // checkpoint
    st[m * 32 + t] = x;
    st[512 + m * 32 + t] = r;
    st[1024 + m * 32 + t] = p;
  }
}

// K0: Gamma -> bf16; block 0 zeros the small scratch region.
__global__ __launch_bounds__(256) void k0_prep(
    const float* __restrict__ Gam, unsigned short* __restrict__ Gbf,
    float* __restrict__ small_zero) {
  const int t = threadIdx.x, b = blockIdx.x;
  const size_t base = ((size_t)b * 256 + t) * 8;
  float4 g0 = *(const float4*)(Gam + base);
  float4 g1 = *(const float4*)(Gam + base + 4);
  *(ushort4*)(Gbf + base) = make_ushort4(f2bf(g0.x), f2bf(g0.y), f2bf(g0.z), f2bf(g0.w));
  *(ushort4*)(Gbf + base + 4) = make_ushort4(f2bf(g1.x), f2bf(g1.y), f2bf(g1.z), f2bf(g1.w));
  if (b == 0)
    for (int i = t; i < 7424; i += 256) small_zero[i] = 0.f;
}

// K1: blocks 0..15: Chebyshev iters 0..4 (checkpoint to st). blocks 16..527:
//     R=exp(sigma-lsh) -> bf16 Rt[N][B] via LDS transpose + colsum via
//     shfl-reduce (no redc staging, 2 barriers per tile).
#define TSTRIDE 132
__global__ __launch_bounds__(512) void k1_rt(
    const float* __restrict__ lsh, const float* __restrict__ sig,
    const float* __restrict__ SR, const unsigned short* __restrict__ Gbf,
    unsigned short* __restrict__ Rt, float* __restrict__ colsum,
    float* __restrict__ st, float* __restrict__ pglob,
    unsigned int* __restrict__ ctr) {
  __shared__ __align__(16) char smraw[36864];
  if (blockIdx.x < NSB) {
    cheb_run(Gbf, SR, st, nullptr, pglob, ctr, smraw, 0, 5);
    return;
  }
  unsigned short* tile = (unsigned short*)smraw;  // [64][132]
  const int t = threadIdx.x;
  const int r = t >> 3, cg = t & 7;   // load: b-row r, 16 consecutive n
  const int jr = t >> 3, cc = t & 7;  // readout: n-row jr, b-chunk cc
  const int wb = blockIdx.x - NSB;
  const size_t bb = (size_t)wb * 64;
  for (int jt = 0; jt < 4; ++jt) {
    const int j0 = jt * 128;
    const size_t off = (bb + r) * NN + j0 + cg * 16;
    float4 s0 = *(const float4*)(sig + off);
    float4 s1 = *(const float4*)(sig + off + 4);
    float4 s2 = *(const float4*)(sig + off + 8);
    float4 s3 = *(const float4*)(sig + off + 12);
    float4 l0 = *(const float4*)(lsh + off);
    float4 l1 = *(const float4*)(lsh + off + 4);
    float4 l2 = *(const float4*)(lsh + off + 8);
    float4 l3 = *(const float4*)(lsh + off + 12);
    ushort4 w0 = make_ushort4(f2bf(__expf(s0.x - l0.x)), f2bf(__expf(s0.y - l0.y)),
                              f2bf(__expf(s0.z - l0.z)), f2bf(__expf(s0.w - l0.w)));
    ushort4 w1 = make_ushort4(f2bf(__expf(s1.x - l1.x)), f2bf(__expf(s1.y - l1.y)),
                              f2bf(__expf(s1.z - l1.z)), f2bf(__expf(s1.w - l1.w)));
    ushort4 w2 = make_ushort4(f2bf(__expf(s2.x - l2.x)), f2bf(__expf(s2.y - l2.y)),
                              f2bf(__expf(s2.z - l2.z)), f2bf(__expf(s2.w - l2.w)));
    ushort4 w3 = make_ushort4(f2bf(__expf(s3.x - l3.x)), f2bf(__expf(s3.y - l3.y)),
                              f2bf(__expf(s3.z - l3.z)), f2bf(__expf(s3.w - l3.w)));
    if (jt) __syncthreads();  // previous readout done
    *(ushort4*)(&tile[r * TSTRIDE + cg * 16 + 0]) = w0;
    *(ushort4*)(&tile[r * TSTRIDE + cg * 16 + 4]) = w1;
    *(ushort4*)(&tile[r * TSTRIDE + cg * 16 + 8]) = w2;
    *(ushort4*)(&tile[r * TSTRIDE + cg * 16 + 12]) = w3;
    __syncthreads();
#pragma unroll
    for (int pass = 0; pass < 2; ++pass) {
      const int j = jr + pass * 64;
      unsigned int u[4];
      float csum = 0.f;
#pragma unroll
      for (int q = 0; q < 4; ++q) {
        unsigned int lo = tile[(cc * 8 + 2 * q) * TSTRIDE + j];
        unsigned int hi = tile[(cc * 8 + 2 * q + 1) * TSTRIDE + j];
        u[q] = lo | (hi << 16);
        csum += bf2f((unsigned short)lo) + bf2f((unsigned short)hi);
      }
      *(uint4*)(Rt + (size_t)(j0 + j) * BB + bb + cc * 8) =
          make_uint4(u[0], u[1], u[2], u[3]);
      csum += __shfl_xor(csum, 1, 64);
      csum += __shfl_xor(csum, 2, 64);
      csum += __shfl_xor(csum, 4, 64);
      if (cc == 0) atomicAdd(&colsum[(wb & 7) * NN + j0 + j], csum);
    }
  }
}

// K2: blocks 0..15: Chebyshev iters 5..9 -> v. blocks 16..335: SYRK with
//     depth-3 counted-vmcnt pipeline (4 LDS buffers, BK=32, 32 chunks):
//     loads stay in flight ACROSS barriers; vmcnt never drains to 0 in the
//     main loop (T3/T4). kc-clustered per XCD for L2 reuse.
__global__ __launch_bounds__(512) void k2_syrk(
    const unsigned short* __restrict__ Rt, const unsigned short* __restrict__ Gbf,
    unsigned short* __restrict__ Cpart, float* __restrict__ v_out,
    float* __restrict__ st, float* __restrict__ pglob,
    unsigned int* __restrict__ ctr) {
  __shared__ __align__(16) char smraw[65536];
  if (blockIdx.x < NSB) {
    cheb_run(Gbf, nullptr, st, v_out, pglob, ctr, smraw, 5, CHEB_IT);
    return;
  }
  unsigned short* smem = (unsigned short*)smraw;  // 4 bufs x (As 4096 | Bs 4096)
  const int wb = blockIdx.x - NSB;  // 0..319 = 8 XCD x 40
  const int kc = (wb & 7) * 4 + (wb >> 3) / NTILE;  // 4 consecutive kc per XCD
  const int tt = (wb >> 3) % NTILE;
  const int ti = (int)((0x3221110000ULL >> (4 * tt)) & 0xF);
  const int tj = (int)((0x3323213210ULL >> (4 * tt)) & 0xF);
  const int i0 = ti * 128, j0 = tj * 128;
  const int diag = (ti == tj);
  const size_t b0 = (size_t)kc * 1024;
  const int t = threadIdx.x, lane = t & 63, wv = t >> 6;
  const int wi = (wv & 3) * 32, wj = (wv >> 2) * 64;
  const int lm = lane & 15, lq = lane >> 4;
  const int srow4 = t >> 2, sc4 = t & 3;
  const int scol4 = (sc4 ^ (srow4 & 3)) * 8;  // swizzled source chunk (involution)
  f32x4 acc[2][4];
#pragma unroll
  for (int a = 0; a < 2; ++a)
#pragma unroll
    for (int b = 0; b < 4; ++b) acc[a][b] = (f32x4){0.f, 0.f, 0.f, 0.f};

#define STAGE2(g)                                                               \
  {                                                                             \
    unsigned short* As_ = smem + ((g) & 3) * 8192;                              \
    const size_t kb = b0 + (size_t)(g) * BKC;                                   \
    gld_lds16(Rt + (size_t)(i0 + srow4) * BB + kb + scol4,                      \
              As_ + srow4 * 32 + sc4 * 8);                                      \
    if (!diag)                                                                  \
      gld_lds16(Rt + (size_t)(j0 + srow4) * BB + kb + scol4,                    \
                As_ + 4096 + srow4 * 32 + sc4 * 8);                             \
  }

  STAGE2(0); STAGE2(1); STAGE2(2);  // depth-3 prologue
  for (int c = 0; c < NCH; ++c) {
    const int pend = (NCH - 1 - c) < 2 ? (NCH - 1 - c) : 2;  // gens in flight past c
    if (diag) {
      if (pend == 2) asm volatile("s_waitcnt vmcnt(2)" ::: "memory");
      else if (pend == 1) asm volatile("s_waitcnt vmcnt(1)" ::: "memory");
      else asm volatile("s_waitcnt vmcnt(0)" ::: "memory");
    } else {
      if (pend == 2) asm volatile("s_waitcnt vmcnt(4)" ::: "memory");
      else if (pend == 1) asm volatile("s_waitcnt vmcnt(2)" ::: "memory");
      else asm volatile("s_waitcnt vmcnt(0)" ::: "memory");
    }
    __builtin_amdgcn_sched_barrier(0);
    __builtin_amdgcn_s_barrier();  // all waves' gen-c staged
    if (c + 3 < NCH) STAGE2(c + 3);
    const unsigned short* As = smem + (c & 3) * 8192;
    const unsigned short* Bs = diag ? As : As + 4096;
    bf16x8 af[2], bfr[4];
#pragma unroll
    for (int g = 0; g < 2; ++g) {
      const int row = wi + g * 16 + lm;
      af[g] = *(const bf16x8*)(As + row * 32 + (lq ^ (row & 3)) * 8);
    }
#pragma unroll
    for (int g = 0; g < 4; ++g) {
      const int row = wj + g * 16 + lm;
      bfr[g] = *(const bf16x8*)(Bs + row * 32 + (lq ^ (row & 3)) * 8);
    }
#pragma unroll
    for (int gm = 0; gm < 2; ++gm)
#pragma unroll
      for (int gn = 0; gn < 4; ++gn)
        acc[gm][gn] = __builtin_amdgcn_mfma_f32_16x16x32_bf16(af[gm], bfr[gn], acc[gm][gn], 0, 0, 0);
    __builtin_amdgcn_sched_barrier(0);
    __builtin_amdgcn_s_barrier();  // readers done before buf reuse
  }
#undef STAGE2

  // epilogue: upper-triangle Cpart (k3 applies off-diag weight 2)
  unsigned short* Cw = Cpart + (size_t)kc * NN * NN;
#pragma unroll
  for (int gm = 0; gm < 2; ++gm) {
    const int rbase = i0 + wi + gm * 16 + lq * 4;
#pragma unroll
    for (int gn = 0; gn < 4; ++gn) {
      const int col = j0 + wj + gn * 16 + lm;
      Cw[(size_t)(rbase + 0) * NN + col] = f2bf(acc[gm][gn][0]);
      Cw[(size_t)(rbase + 1) * NN + col] = f2bf(acc[gm][gn][1]);
      Cw[(size_t)(rbase + 2) * NN + col] = f2bf(acc[gm][gn][2]);
      Cw[(size_t)(rbase + 3) * NN + col] = f2bf(acc[gm][gn][3]);
    }
  }
}

// K3: secondsum = sum over upper-tri tiles of w * v_i Gamma_ij C_ij v_j.
__global__ __launch_bounds__(256) void k3_contract(
    const float* __restrict__ Gamma, const unsigned short* __restrict__ Cpart,
    const float* __restrict__ v, float* __restrict__ secondsum) {
  __shared__ float red[4];
  const int t = threadIdx.x;
  const int tidx = blockIdx.x >> 4;
  const int sub = ((blockIdx.x & 15) << 10) + t * 4;
  const int ti = (int)((0x3221110000ULL >> (4 * tidx)) & 0xF);
  const int tj = (int)((0x3323213210ULL >> (4 * tidx)) & 0xF);
  const float w = (ti == tj) ? 1.f : 2.f;
  const int i = ti * 128 + (sub >> 7);
  const int j = tj * 128 + (sub & 127);
  const size_t e = (size_t)i * NN + j;
  float cx = 0, cy = 0, cz = 0, cw = 0;
  for (int pp = 0; pp < NPART; ++pp) {
    ushort4 u = *(const ushort4*)(Cpart + (size_t)pp * NN * NN + e);
    cx += bf2f(u.x); cy += bf2f(u.y); cz += bf2f(u.z); cw += bf2f(u.w);
  }
  float4 g = *(const float4*)(Gamma + e);
  float4 vj = *(const float4*)(v + j);
  float vi = v[i];
  float p = w * vi * (g.x * cx * vj.x + g.y * cy * vj.y + g.z * cz * vj.z + g.w * cw * vj.w);
  p = wave_reduce(p);
  if ((t & 63) == 0) red[t >> 6] = p;
  __syncthreads();
  if (t == 0) atomicAdd(secondsum, red[0] + red[1] + red[2] + red[3]);
}

// K4: loss = -( sum_j (colsum_j/B) v_j SR_j / k - secondsum/(B*2k) )
__global__ __launch_bounds__(512) void k4_final(
    const float* __restrict__ colsum, const float* __restrict__ v,
    const float* __restrict__ SR, const float* __restrict__ secondsum,
    const int* __restrict__ kp, float* __restrict__ out) {
  __shared__ float red[8];
  const int t = threadIdx.x;
  float cs = 0;
#pragma unroll
  for (int bk = 0; bk < 8; ++bk) cs += colsum[bk * NN + t];
  float f = (cs * (1.0f / BB)) * v[t] * SR[t];
  f = wave_reduce(f);
  if ((t & 63) == 0) red[t >> 6] = f;
  __syncthreads();
  if (t == 0) {
    float first = 0;
#pragma unroll
    for (int i = 0; i < 8; ++i) first += red[i];
    float kk = (float)kp[0];
    float sec = secondsum[0] / ((float)BB * 2.0f * kk);
    out[0] = -(first / kk - sec);
  }
}

extern "C" void kernel_launch(void* const* d_in, const int* in_sizes, int n_in,
                              void* d_out, int out_size, void* d_ws, size_t ws_size,
                              hipStream_t stream) {
  const float* lsh = (const float*)d_in[0];
  const float* sig = (const float*)d_in[1];
  const float* SR = (const float*)d_in[2];
  const float* Gam = (const float*)d_in[3];
  const int* kp = (const int*)d_in[4];
  char* ws = (char*)d_ws;
  // layout: Cpart 16MB | colsum 4096f secsum 64f v 512f ctr 16u pglob 1024f st 1536f
  //         | Gbf 512KB | Rt 32MB
  unsigned short* Cpart = (unsigned short*)ws;
  const size_t coff = (size_t)NPART * NN * NN * sizeof(unsigned short);  // 16 MB
  float* colsum = (float*)(ws + coff);
  float* secsum = colsum + 4096;
  float* v = secsum + 64;
  unsigned int* ctr = (unsigned int*)(v + 512);
  float* pglob = (float*)(ctr + 16);
  float* st = pglob + 1024;
  unsigned short* Gbf = (unsigned short*)(ws + coff + (32 << 10));
  unsigned short* Rt = (unsigned short*)(ws + coff + (32 << 10) + (512 << 10));

  k0_prep<<<128, 256, 0, stream>>>(Gam, Gbf, colsum);
  k1_rt<<<NSB + 512, 512, 0, stream>>>(lsh, sig, SR, Gbf, Rt, colsum, st, pglob, ctr);
  k2_syrk<<<NSB + NPART * NTILE, 512, 0, stream>>>(Rt, Gbf, Cpart, v, st, pglob, ctr + 1);
  k3_contract<<<160, 256, 0, stream>>>(Gam, Cpart, v, secsum);
  k4_final<<<1, 512, 0, stream>>>(colsum, v, SR, secsum, kp, (float*)d_out);
}